// Round 13
// baseline (107.480 us; speedup 1.0000x reference)
//
#include <hip/hip_runtime.h>
#include <math.h>

// Problem constants (from reference setup_inputs)
#define B   16
#define NH  1024
#define NO  2048
#define DQ  24

#define ALPHA_FOCAL 0.25f
#define MARGIN_PEN  0.005f
#define RADIUS_REP  0.015f
#define R2REP       (RADIUS_REP * RADIUS_REP)

// ws layout:
//   float [0..16) scalar slots:
//     0,1: hand cd dir0/dir1   2,3: obj cd dir0/dir1 (weighted)
//     4: repulsion shifted sum S=sum min(d,R) incl diag (weighted)
//     5: penetration (weighted)  6: focal  7: qpos  8: pose (weighted)
//     9: valid   15: combine ticket counter (uint)
//   uint [16..16+131072): per-row ~bits(min d2) via atomicMax (init 0).
//   Identity slot mapping (row index within segment == slot).
//     hand d0 [0,16384) hand d1 [16384,32768)
//     obj d0 [32768,65536) obj d1 [65536,98304) pen [98304,131072)
#define WS_SCAL    16
#define ROWS_TOTAL 131072

typedef float v2f __attribute__((ext_vector_type(2)));
typedef float v4f __attribute__((ext_vector_type(4)));

__device__ inline float wsqrt(float x) { return __builtin_amdgcn_sqrtf(x); }

__device__ inline float block_reduce_sum(float v, float* red) {
    #pragma unroll
    for (int off = 32; off > 0; off >>= 1) v += __shfl_down(v, off, 64);
    int lane = threadIdx.x & 63;
    int wid  = threadIdx.x >> 6;
    if (lane == 0) red[wid] = v;
    __syncthreads();
    float s = 0.f;
    if (threadIdx.x == 0) s = red[0] + red[1] + red[2] + red[3];
    __syncthreads();
    return s;   // valid in thread 0 only
}

// 2051 blocks (0-2 small losses; 3.. pairwise). Wave w of block k-3 is an
// independent unit (no __syncthreads): 512 rows (8 contiguous rows/lane,
// 4 row-pairs) x 64 Q cols staged in a wave-private LDS region.
// 8192 pairwise waves = 32/CU = 8/SIMD (launch_bounds(256,8), VGPR<=64).
//   w=0: repulsion    k -> b(16) x rc(4) x jc(32)
//   w=1: obj cd dir0  k -> b(16) x rc(4) x jc(32)
//   w=2: obj cd dir1  k -> b(16) x rc(4) x jc(32)
//   w=3: k<1024 hand  dir(2) x b(16) x rc(2) x jc(16)
//        else   pen   b(16) x rc(4) x jc(16)
__global__ __launch_bounds__(256, 8) void pairwise_kernel(
    const float* __restrict__ pred_hand, const float* __restrict__ pred_obj,
    const float* __restrict__ gt_hand,   const float* __restrict__ gt_obj,
    const float* __restrict__ has_contact,
    const float* __restrict__ logits,    const float* __restrict__ gt_contact,
    const float* __restrict__ pred_qpos, const float* __restrict__ gt_qpos,
    const float* __restrict__ pred_pose, const float* __restrict__ gt_pose,
    float* __restrict__ ws)
{
    __shared__ v4f qs[256];     // 4 KiB: 4 waves x 64 cols {-2x,-2y,-2z,|q|^2}
    __shared__ float red[4];

    const int tid = threadIdx.x;
    const int blk = blockIdx.x;

    if (blk < 3) {              // small fused loss terms
        if (blk == 0) {
            float fsum = 0.f;
            for (int i = tid; i < B*NH; i += 256) {
                float l = logits[i];
                float y = gt_contact[i];
                float bce = fmaxf(l, 0.f) - l*y + log1pf(expf(-fabsf(l)));
                float pt  = expf(-bce);
                float om  = 1.f - pt;
                fsum += ALPHA_FOCAL * om * om * bce;
            }
            float fT = block_reduce_sum(fsum, red);
            if (tid == 0) atomicAdd(&ws[6], fT);
        } else if (blk == 1) {
            float qsum = 0.f;
            for (int i = tid; i < B*DQ; i += 256) {
                float d = pred_qpos[i] - gt_qpos[i];
                qsum += d*d;
            }
            float qT = block_reduce_sum(qsum, red);
            if (tid == 0) atomicAdd(&ws[7], qT);
        } else {
            float psum = 0.f, vsum = 0.f;
            if (tid < B) {
                const float* pp = pred_pose + tid*7;
                const float* gp = gt_pose   + tid*7;
                float lt = (fabsf(pp[0]-gp[0]) + fabsf(pp[1]-gp[1]) + fabsf(pp[2]-gp[2])) * (1.f/3.f);
                float npn = wsqrt(pp[3]*pp[3] + pp[4]*pp[4] + pp[5]*pp[5] + pp[6]*pp[6]);
                float ngn = wsqrt(gp[3]*gp[3] + gp[4]*gp[4] + gp[5]*gp[5] + gp[6]*gp[6]);
                float dot = (pp[3]*gp[3] + pp[4]*gp[4] + pp[5]*gp[5] + pp[6]*gp[6]) / (npn * ngn);
                float lr = 1.f - fabsf(dot);
                psum = (lt + 0.1f*lr) * has_contact[tid];
                vsum = has_contact[tid];
            }
            float pT = block_reduce_sum(psum, red);
            float vT = block_reduce_sum(vsum, red);
            if (tid == 0) { atomicAdd(&ws[8], pT); atomicAdd(&ws[9], vT); }
        }
        return;
    }

    const int w = tid >> 6;
    const int l = tid & 63;
    const int k = blk - 3;

    unsigned* rowmin = (unsigned*)(ws + WS_SCAL);
    const float* Pb; const float* Qb;
    int b, rowbase = 0, rep = 0;

    if (w == 0) {                           // repulsion
        b = k >> 7; int rc = (k >> 5) & 3, jc = k & 31;
        Pb = pred_obj + b*NO*3 + rc*512*3;
        Qb = pred_obj + b*NO*3 + jc*64*3;
        rep = 1;
    } else if (w == 1) {                    // obj chamfer dir0
        b = k >> 7; int rc = (k >> 5) & 3, jc = k & 31;
        Pb = pred_obj + b*NO*3 + rc*512*3;
        Qb = gt_obj   + b*NO*3 + jc*64*3;
        rowbase = 32768 + b*2048 + rc*512;
    } else if (w == 2) {                    // obj chamfer dir1
        b = k >> 7; int rc = (k >> 5) & 3, jc = k & 31;
        Pb = gt_obj   + b*NO*3 + rc*512*3;
        Qb = pred_obj + b*NO*3 + jc*64*3;
        rowbase = 65536 + b*2048 + rc*512;
    } else if (k < 1024) {                  // hand chamfer
        int dir = k >> 9, t = k & 511;
        b = t >> 5; int rc = (t >> 4) & 1, jc = t & 15;
        Pb = (dir ? gt_hand : pred_hand) + b*NH*3 + rc*512*3;
        Qb = (dir ? pred_hand : gt_hand) + b*NH*3 + jc*64*3;
        rowbase = dir*16384 + b*1024 + rc*512;
    } else {                                // penetration
        int t = k - 1024;
        b = t >> 6; int rc = (t >> 4) & 3, jc = t & 15;
        Pb = pred_obj  + b*NO*3 + rc*512*3;
        Qb = pred_hand + b*NH*3 + jc*64*3;
        rowbase = 98304 + b*2048 + rc*512;
    }

    // This lane's 8 contiguous P rows: 24 floats = 6 x dwordx4
    v4f f4[6];
    const v4f* pv = (const v4f*)(Pb + l*24);
    #pragma unroll
    for (int i = 0; i < 6; ++i) f4[i] = pv[i];
    const float* f = (const float*)f4;

    // Stage this wave's 64 Q cols into its private LDS region
    {
        const float* qp = Qb + l*3;
        float x = qp[0], y = qp[1], z = qp[2];
        qs[(w << 6) | l] = (v4f){-2.f*x, -2.f*y, -2.f*z, fmaf(x, x, fmaf(y, y, z*z))};
    }
    // No __syncthreads: each wave reads only its own region (lgkmcnt orders).

    // 4 row-pairs (rows 2kk, 2kk+1 of this lane's 8)
    v2f px2[4], py2[4], pz2[4];
    #pragma unroll
    for (int kk = 0; kk < 4; ++kk) {
        px2[kk] = (v2f){f[6*kk+0], f[6*kk+3]};
        py2[kk] = (v2f){f[6*kk+1], f[6*kk+4]};
        pz2[kk] = (v2f){f[6*kk+2], f[6*kk+5]};
    }

    const v4f* qw = qs + (w << 6);

    if (rep) {
        v2f pn2[4];
        #pragma unroll
        for (int kk = 0; kk < 4; ++kk)
            pn2[kk] = __builtin_elementwise_fma(px2[kk], px2[kk],
                      __builtin_elementwise_fma(py2[kk], py2[kk], pz2[kk]*pz2[kk]));
        v2f sacc = (v2f){0.f, 0.f};
        const v2f vR = (v2f){RADIUS_REP, RADIUS_REP};
        auto rstep = [&](v4f Q) {
            v2f bx = __builtin_shufflevector(Q, Q, 0, 0);
            v2f by = __builtin_shufflevector(Q, Q, 1, 1);
            v2f bz = __builtin_shufflevector(Q, Q, 2, 2);
            v2f bw = __builtin_shufflevector(Q, Q, 3, 3);
            #pragma unroll
            for (int kk = 0; kk < 4; ++kk) {
                v2f t = __builtin_elementwise_fma(bz, pz2[kk], bw);
                t     = __builtin_elementwise_fma(by, py2[kk], t);
                t     = __builtin_elementwise_fma(bx, px2[kk], t);
                v2f d2 = t + pn2[kk];
                if (__any(fminf(d2.x, d2.y) < R2REP)) {
                    // min(d,R) exactly (diag d2~0 -> ~1e-6, fixed in finalize)
                    v2f dd;
                    dd.x = wsqrt(__builtin_amdgcn_fmed3f(d2.x, 1e-12f, R2REP));
                    dd.y = wsqrt(__builtin_amdgcn_fmed3f(d2.y, 1e-12f, R2REP));
                    sacc += dd;
                } else {
                    sacc += vR;     // min(d,R) = R for both elements
                }
            }
        };
        v4f Q0 = qw[0], Q1 = qw[1], Q2 = qw[2], Q3 = qw[3];
        for (int j = 0; j < 60; j += 4) {
            rstep(Q0); Q0 = qw[j+4];
            rstep(Q1); Q1 = qw[j+5];
            rstep(Q2); Q2 = qw[j+6];
            rstep(Q3); Q3 = qw[j+7];
        }
        rstep(Q0); rstep(Q1); rstep(Q2); rstep(Q3);

        float s = sacc.x + sacc.y;
        #pragma unroll
        for (int off = 32; off > 0; off >>= 1) s += __shfl_down(s, off, 64);
        if (l == 0) atomicAdd(&ws[4], s * has_contact[b]);
    } else {
        v2f m2[4];
        #pragma unroll
        for (int kk = 0; kk < 4; ++kk) m2[kk] = (v2f){1e30f, 1e30f};
        auto cstep = [&](v4f Q) {
            v2f bx = __builtin_shufflevector(Q, Q, 0, 0);
            v2f by = __builtin_shufflevector(Q, Q, 1, 1);
            v2f bz = __builtin_shufflevector(Q, Q, 2, 2);
            v2f bw = __builtin_shufflevector(Q, Q, 3, 3);
            #pragma unroll
            for (int kk = 0; kk < 4; ++kk) {
                v2f t = __builtin_elementwise_fma(bz, pz2[kk], bw);
                t     = __builtin_elementwise_fma(by, py2[kk], t);
                t     = __builtin_elementwise_fma(bx, px2[kk], t);
                m2[kk] = __builtin_elementwise_min(m2[kk], t);
            }
        };
        v4f Q0 = qw[0], Q1 = qw[1], Q2 = qw[2], Q3 = qw[3];
        for (int j = 0; j < 60; j += 4) {
            cstep(Q0); Q0 = qw[j+4];
            cstep(Q1); Q1 = qw[j+5];
            cstep(Q2); Q2 = qw[j+6];
            cstep(Q3); Q3 = qw[j+7];
        }
        cstep(Q0); cstep(Q1); cstep(Q2); cstep(Q3);

        // Identity slot mapping: row l*8 + 2kk + e (R7-style, 12MB regime)
        #pragma unroll
        for (int kk = 0; kk < 4; ++kk) {
            #pragma unroll
            for (int e = 0; e < 2; ++e) {
                float x = px2[kk][e], y = py2[kk][e], z = pz2[kk][e];
                float pn = fmaf(x, x, fmaf(y, y, z*z));
                float mv = m2[kk][e] + pn;
                unsigned c = ~__float_as_uint(fmaxf(mv, 1e-12f));
                atomicMax(&rowmin[rowbase + l*8 + 2*kk + e], c);
            }
        }
    }
}

// 80 blocks: reduce per-row mins; last block (ticket) finalizes into out[0].
//  [0,32): hand (dir x b)  [32,64): obj (dir x b)  [64,80): pen (b)
__global__ __launch_bounds__(256) void combine_kernel(
    const float* __restrict__ has_contact, float* __restrict__ ws,
    float* __restrict__ out)
{
    __shared__ float red[4];
    const unsigned* rowmin = (const unsigned*)(ws + WS_SCAL);
    int blk = blockIdx.x;
    int tid = threadIdx.x;

    int slot, rows, base, pen = 0;
    float w = 1.f;
    if (blk < 32) {
        int dir = blk >> 4, b = blk & 15;
        slot = dir; rows = 1024; base = dir*16384 + b*1024;
    } else if (blk < 64) {
        int idx = blk - 32; int dir = idx >> 4, b = idx & 15;
        slot = 2 + dir; rows = 2048; base = 32768 + dir*32768 + b*2048;
        w = has_contact[b];
    } else {
        int b = blk - 64;
        slot = 5; rows = 2048; base = 98304 + b*2048;
        w = has_contact[b]; pen = 1;
    }
    float s = 0.f;
    for (int n = tid; n < rows; n += 256) {
        float d = wsqrt(__uint_as_float(~rowmin[base + n]));
        s += pen ? fmaxf(MARGIN_PEN - d, 0.f) : d;
    }
    float bs = block_reduce_sum(s, red);
    if (tid == 0) {
        atomicAdd(&ws[slot], bs * w);
        __threadfence();
        unsigned* cnt = (unsigned*)(ws + 15);
        unsigned old = atomicAdd(cnt, 1u);
        if (old == 79u) {                       // last block finalizes
            __threadfence();
            float s0 = atomicAdd(&ws[0], 0.f), s1 = atomicAdd(&ws[1], 0.f);
            float s2 = atomicAdd(&ws[2], 0.f), s3 = atomicAdd(&ws[3], 0.f);
            float s4 = atomicAdd(&ws[4], 0.f), s5 = atomicAdd(&ws[5], 0.f);
            float s6 = atomicAdd(&ws[6], 0.f), s7 = atomicAdd(&ws[7], 0.f);
            float s8 = atomicAdd(&ws[8], 0.f), s9 = atomicAdd(&ws[9], 0.f);
            double vT    = s9;
            double valid = vT + 1e-6;
            double NOd   = (double)NO;
            // repulsion: sum relu(R-d) = hc-weighted (NO^2*R - S) minus diagonal
            double repw  = vT*NOd*NOd*(double)RADIUS_REP - (double)s4;
            double repx  = repw - vT*NOd*((double)RADIUS_REP - 1e-6);
            double loss_cd_hand = ((double)s0 + (double)s1) / (double)(B*NH);
            double loss_cd_obj  = ((double)s2 + (double)s3) / (NOd * valid);
            double loss_rep     = repx / (NOd * NOd * valid);
            double loss_pen     = (double)s5 / (NOd * valid);
            double loss_pose    = (double)s8 / valid;
            double loss_qpos    = (double)s7 / (double)(B*DQ);
            double loss_contact = (double)s6 / (double)(B*NH);
            double total = 5.0*loss_cd_hand + 5.0*loss_cd_obj + 2.0*loss_pose
                         + 1.0*loss_qpos + 2.0*loss_contact
                         + 0.5*loss_rep + 0.5*loss_pen;
            out[0] = (float)total;
        }
    }
}

extern "C" void kernel_launch(void* const* d_in, const int* in_sizes, int n_in,
                              void* d_out, int out_size, void* d_ws, size_t ws_size,
                              hipStream_t stream) {
    const float* pred_hand   = (const float*)d_in[0];
    const float* pred_obj    = (const float*)d_in[1];
    const float* pred_pose   = (const float*)d_in[2];
    const float* pred_qpos   = (const float*)d_in[3];
    const float* logits      = (const float*)d_in[4];
    const float* gt_hand     = (const float*)d_in[5];
    const float* gt_obj      = (const float*)d_in[6];
    const float* gt_pose     = (const float*)d_in[7];
    const float* gt_qpos     = (const float*)d_in[8];
    const float* gt_contact  = (const float*)d_in[9];
    const float* has_contact = (const float*)d_in[10];

    float* ws = (float*)d_ws;

    // single init: scalars+ticket <- 0, rowmin (complement-coded) <- 0
    hipMemsetAsync(ws, 0, (WS_SCAL + ROWS_TOTAL) * sizeof(float), stream);

    pairwise_kernel<<<2051, 256, 0, stream>>>(pred_hand, pred_obj, gt_hand, gt_obj,
                                              has_contact, logits, gt_contact,
                                              pred_qpos, gt_qpos, pred_pose, gt_pose, ws);
    combine_kernel<<<80, 256, 0, stream>>>(has_contact, ws, (float*)d_out);
}

// Round 14
// 67.871 us; speedup vs baseline: 1.5836x; 1.5836x over previous
//
#include <hip/hip_runtime.h>
#include <math.h>

// Problem constants (from reference setup_inputs)
#define B   16
#define NH  1024
#define NO  2048
#define DQ  24

#define ALPHA_FOCAL 0.25f
#define MARGIN_PEN  0.005f
#define RADIUS_REP  0.015f
#define R2REP       (RADIUS_REP * RADIUS_REP)

// ws layout:
//   float [0..16) scalar slots:
//     0,1: hand cd dir0/dir1   2,3: obj cd dir0/dir1 (weighted)
//     4: repulsion shifted sum S=sum min(d,R) incl diag (weighted)
//     5: penetration (weighted)  6: focal  7: qpos  8: pose (weighted)
//     9: valid   15: combine ticket counter (uint)
//   uint [16..16+131072): per-row ~bits(min d2) via atomicMax (init 0).
//   Identity row mapping. hand d0 [0,16384) hand d1 [16384,32768)
//   obj d0 [32768,65536) obj d1 [65536,98304) pen [98304,131072)
#define WS_SCAL    16
#define ROWS_TOTAL 131072

typedef float v2f __attribute__((ext_vector_type(2)));
typedef float v4f __attribute__((ext_vector_type(4)));

__device__ inline float wsqrt(float x) { return __builtin_amdgcn_sqrtf(x); }

__device__ inline float block_reduce_sum(float v, float* red) {
    #pragma unroll
    for (int off = 32; off > 0; off >>= 1) v += __shfl_down(v, off, 64);
    int lane = threadIdx.x & 63;
    int wid  = threadIdx.x >> 6;
    if (lane == 0) red[wid] = v;
    __syncthreads();
    float s = 0.f;
    if (threadIdx.x == 0) s = red[0] + red[1] + red[2] + red[3];
    __syncthreads();
    return s;   // valid in thread 0 only
}

// 2051 blocks (0-2: small losses). Pairwise block = 512 rows x 256 cols;
// its 4 waves are 4 col-chunks (w*64) of the SAME row-set; per-wave row
// mins merge in LDS; TWO lane-consecutive atomicMax per thread.
// jg (col-group) is the FASTEST block digit -> the 8 (obj) / 4 (hand,pen)
// blocks sharing a row-set are consecutive => co-dispatched same round
// (R7's low-traffic regime). 2048 blocks = 8/CU -> 32 waves/CU = 8/SIMD.
//  k=blk-3: [   0,1024): obj cd  dir(2) x b(16) x rc(4) x jg(8)
//           [1024,1536): rep     b(16) x rc(4) x jg(8)   (sum only)
//           [1536,1792): hand cd dir(2) x b(16) x rc(2) x jg(4)
//           [1792,2048): pen     b(16) x rc(4) x jg(4)
__global__ __launch_bounds__(256, 8) void pairwise_kernel(
    const float* __restrict__ pred_hand, const float* __restrict__ pred_obj,
    const float* __restrict__ gt_hand,   const float* __restrict__ gt_obj,
    const float* __restrict__ has_contact,
    const float* __restrict__ logits,    const float* __restrict__ gt_contact,
    const float* __restrict__ pred_qpos, const float* __restrict__ gt_qpos,
    const float* __restrict__ pred_pose, const float* __restrict__ gt_pose,
    float* __restrict__ ws)
{
    __shared__ v4f   qs[256];       // 4 KiB: 4 waves x 64 cols {-2x,-2y,-2z,|q|^2}
    __shared__ float mbuf[4][512];  // 8 KiB: per-wave row mins (pn folded)
    __shared__ float red[4];

    const int tid = threadIdx.x;
    const int blk = blockIdx.x;

    if (blk < 3) {              // small fused loss terms
        if (blk == 0) {
            float fsum = 0.f;
            for (int i = tid; i < B*NH; i += 256) {
                float l = logits[i];
                float y = gt_contact[i];
                float bce = fmaxf(l, 0.f) - l*y + log1pf(expf(-fabsf(l)));
                float pt  = expf(-bce);
                float om  = 1.f - pt;
                fsum += ALPHA_FOCAL * om * om * bce;
            }
            float fT = block_reduce_sum(fsum, red);
            if (tid == 0) atomicAdd(&ws[6], fT);
        } else if (blk == 1) {
            float qsum = 0.f;
            for (int i = tid; i < B*DQ; i += 256) {
                float d = pred_qpos[i] - gt_qpos[i];
                qsum += d*d;
            }
            float qT = block_reduce_sum(qsum, red);
            if (tid == 0) atomicAdd(&ws[7], qT);
        } else {
            float psum = 0.f, vsum = 0.f;
            if (tid < B) {
                const float* pp = pred_pose + tid*7;
                const float* gp = gt_pose   + tid*7;
                float lt = (fabsf(pp[0]-gp[0]) + fabsf(pp[1]-gp[1]) + fabsf(pp[2]-gp[2])) * (1.f/3.f);
                float npn = wsqrt(pp[3]*pp[3] + pp[4]*pp[4] + pp[5]*pp[5] + pp[6]*pp[6]);
                float ngn = wsqrt(gp[3]*gp[3] + gp[4]*gp[4] + gp[5]*gp[5] + gp[6]*gp[6]);
                float dot = (pp[3]*gp[3] + pp[4]*gp[4] + pp[5]*gp[5] + pp[6]*gp[6]) / (npn * ngn);
                float lr = 1.f - fabsf(dot);
                psum = (lt + 0.1f*lr) * has_contact[tid];
                vsum = has_contact[tid];
            }
            float pT = block_reduce_sum(psum, red);
            float vT = block_reduce_sum(vsum, red);
            if (tid == 0) { atomicAdd(&ws[8], pT); atomicAdd(&ws[9], vT); }
        }
        return;
    }

    const int w = tid >> 6;
    const int l = tid & 63;
    const int k = blk - 3;

    unsigned* rowmin = (unsigned*)(ws + WS_SCAL);
    const float* Pb; const float* Qb;
    int b, rowbase = 0, rep = 0;

    if (k < 1024) {                         // obj chamfer
        int dir = k >> 9, t = k & 511;
        b = t >> 5; int rc = (t >> 3) & 3, jg = t & 7;
        Pb = (dir ? gt_obj : pred_obj) + b*NO*3 + rc*512*3;
        Qb = (dir ? pred_obj : gt_obj) + b*NO*3 + jg*256*3;
        rowbase = 32768 + dir*32768 + b*2048 + rc*512;
    } else if (k < 1536) {                  // repulsion
        int t = k - 1024;
        b = t >> 5; int rc = (t >> 3) & 3, jg = t & 7;
        Pb = pred_obj + b*NO*3 + rc*512*3;
        Qb = pred_obj + b*NO*3 + jg*256*3;
        rep = 1;
    } else if (k < 1792) {                  // hand chamfer
        int t = k - 1536;
        int dir = t >> 7, r = t & 127;
        b = r >> 3; int rc = (r >> 2) & 1, jg = r & 3;
        Pb = (dir ? gt_hand : pred_hand) + b*NH*3 + rc*512*3;
        Qb = (dir ? pred_hand : gt_hand) + b*NH*3 + jg*256*3;
        rowbase = dir*16384 + b*1024 + rc*512;
    } else {                                // penetration
        int t = k - 1792;
        b = t >> 4; int rc = (t >> 2) & 3, jg = t & 3;
        Pb = pred_obj  + b*NO*3 + rc*512*3;
        Qb = pred_hand + b*NH*3 + jg*256*3;
        rowbase = 98304 + b*2048 + rc*512;
    }

    // This lane's 8 contiguous P rows: 24 floats = 6 x dwordx4
    v4f f4[6];
    const v4f* pv = (const v4f*)(Pb + l*24);
    #pragma unroll
    for (int i = 0; i < 6; ++i) f4[i] = pv[i];
    const float* f = (const float*)f4;

    // Stage this wave's 64 Q cols (block cols w*64..w*64+63)
    {
        const float* qp = Qb + ((w << 6) | l)*3;
        float x = qp[0], y = qp[1], z = qp[2];
        qs[(w << 6) | l] = (v4f){-2.f*x, -2.f*y, -2.f*z, fmaf(x, x, fmaf(y, y, z*z))};
    }
    // Each wave reads only its own qs region (lgkmcnt orders write->read).

    // 4 row-pairs (rows 2kk, 2kk+1 of this lane's 8)
    v2f px2[4], py2[4], pz2[4];
    #pragma unroll
    for (int kk = 0; kk < 4; ++kk) {
        px2[kk] = (v2f){f[6*kk+0], f[6*kk+3]};
        py2[kk] = (v2f){f[6*kk+1], f[6*kk+4]};
        pz2[kk] = (v2f){f[6*kk+2], f[6*kk+5]};
    }

    const v4f* qw = qs + (w << 6);

    if (rep) {
        v2f pn2[4];
        #pragma unroll
        for (int kk = 0; kk < 4; ++kk)
            pn2[kk] = __builtin_elementwise_fma(px2[kk], px2[kk],
                      __builtin_elementwise_fma(py2[kk], py2[kk], pz2[kk]*pz2[kk]));
        v2f sacc = (v2f){0.f, 0.f};
        const v2f vR = (v2f){RADIUS_REP, RADIUS_REP};
        auto rstep = [&](v4f Q) {
            v2f bx = __builtin_shufflevector(Q, Q, 0, 0);
            v2f by = __builtin_shufflevector(Q, Q, 1, 1);
            v2f bz = __builtin_shufflevector(Q, Q, 2, 2);
            v2f bw = __builtin_shufflevector(Q, Q, 3, 3);
            #pragma unroll
            for (int kk = 0; kk < 4; ++kk) {
                v2f t = __builtin_elementwise_fma(bz, pz2[kk], bw);
                t     = __builtin_elementwise_fma(by, py2[kk], t);
                t     = __builtin_elementwise_fma(bx, px2[kk], t);
                v2f d2 = t + pn2[kk];
                if (__any(fminf(d2.x, d2.y) < R2REP)) {
                    // min(d,R) exactly (diag d2~0 -> ~1e-6, fixed in finalize)
                    v2f dd;
                    dd.x = wsqrt(__builtin_amdgcn_fmed3f(d2.x, 1e-12f, R2REP));
                    dd.y = wsqrt(__builtin_amdgcn_fmed3f(d2.y, 1e-12f, R2REP));
                    sacc += dd;
                } else {
                    sacc += vR;     // min(d,R) = R for both elements
                }
            }
        };
        v4f Q0 = qw[0], Q1 = qw[1], Q2 = qw[2], Q3 = qw[3];
        for (int j = 0; j < 60; j += 4) {
            rstep(Q0); Q0 = qw[j+4];
            rstep(Q1); Q1 = qw[j+5];
            rstep(Q2); Q2 = qw[j+6];
            rstep(Q3); Q3 = qw[j+7];
        }
        rstep(Q0); rstep(Q1); rstep(Q2); rstep(Q3);

        float bs = block_reduce_sum(sacc.x + sacc.y, red);
        if (tid == 0) atomicAdd(&ws[4], bs * has_contact[b]);
    } else {
        v2f m2[4];
        #pragma unroll
        for (int kk = 0; kk < 4; ++kk) m2[kk] = (v2f){1e30f, 1e30f};
        auto cstep = [&](v4f Q) {
            v2f bx = __builtin_shufflevector(Q, Q, 0, 0);
            v2f by = __builtin_shufflevector(Q, Q, 1, 1);
            v2f bz = __builtin_shufflevector(Q, Q, 2, 2);
            v2f bw = __builtin_shufflevector(Q, Q, 3, 3);
            #pragma unroll
            for (int kk = 0; kk < 4; ++kk) {
                v2f t = __builtin_elementwise_fma(bz, pz2[kk], bw);
                t     = __builtin_elementwise_fma(by, py2[kk], t);
                t     = __builtin_elementwise_fma(bx, px2[kk], t);
                m2[kk] = __builtin_elementwise_min(m2[kk], t);
            }
        };
        v4f Q0 = qw[0], Q1 = qw[1], Q2 = qw[2], Q3 = qw[3];
        for (int j = 0; j < 60; j += 4) {
            cstep(Q0); Q0 = qw[j+4];
            cstep(Q1); Q1 = qw[j+5];
            cstep(Q2); Q2 = qw[j+6];
            cstep(Q3); Q3 = qw[j+7];
        }
        cstep(Q0); cstep(Q1); cstep(Q2); cstep(Q3);

        // Per-wave mins (pn folded: exact for min-merge) -> LDS
        #pragma unroll
        for (int kk = 0; kk < 4; ++kk) {
            #pragma unroll
            for (int e = 0; e < 2; ++e) {
                float x = px2[kk][e], y = py2[kk][e], z = pz2[kk][e];
                float pn = fmaf(x, x, fmaf(y, y, z*z));
                mbuf[w][l*8 + 2*kk + e] = m2[kk][e] + pn;
            }
        }
        __syncthreads();
        // Merge 4 waves; rows tid and tid+256: lane-consecutive atomics
        #pragma unroll
        for (int q = 0; q < 2; ++q) {
            int r = (q << 8) + tid;
            float mv = fminf(fminf(mbuf[0][r], mbuf[1][r]),
                             fminf(mbuf[2][r], mbuf[3][r]));
            unsigned c = ~__float_as_uint(fmaxf(mv, 1e-12f));
            atomicMax(&rowmin[rowbase + r], c);
        }
    }
}

// 80 blocks: reduce per-row mins; last block (ticket) finalizes into out[0].
//  [0,32): hand (dir x b)  [32,64): obj (dir x b)  [64,80): pen (b)
__global__ __launch_bounds__(256) void combine_kernel(
    const float* __restrict__ has_contact, float* __restrict__ ws,
    float* __restrict__ out)
{
    __shared__ float red[4];
    const unsigned* rowmin = (const unsigned*)(ws + WS_SCAL);
    int blk = blockIdx.x;
    int tid = threadIdx.x;

    int slot, rows, base, pen = 0;
    float w = 1.f;
    if (blk < 32) {
        int dir = blk >> 4, b = blk & 15;
        slot = dir; rows = 1024; base = dir*16384 + b*1024;
    } else if (blk < 64) {
        int idx = blk - 32; int dir = idx >> 4, b = idx & 15;
        slot = 2 + dir; rows = 2048; base = 32768 + dir*32768 + b*2048;
        w = has_contact[b];
    } else {
        int b = blk - 64;
        slot = 5; rows = 2048; base = 98304 + b*2048;
        w = has_contact[b]; pen = 1;
    }
    float s = 0.f;
    for (int n = tid; n < rows; n += 256) {
        float d = wsqrt(__uint_as_float(~rowmin[base + n]));
        s += pen ? fmaxf(MARGIN_PEN - d, 0.f) : d;
    }
    float bs = block_reduce_sum(s, red);
    if (tid == 0) {
        atomicAdd(&ws[slot], bs * w);
        __threadfence();
        unsigned* cnt = (unsigned*)(ws + 15);
        unsigned old = atomicAdd(cnt, 1u);
        if (old == 79u) {                       // last block finalizes
            __threadfence();
            float s0 = atomicAdd(&ws[0], 0.f), s1 = atomicAdd(&ws[1], 0.f);
            float s2 = atomicAdd(&ws[2], 0.f), s3 = atomicAdd(&ws[3], 0.f);
            float s4 = atomicAdd(&ws[4], 0.f), s5 = atomicAdd(&ws[5], 0.f);
            float s6 = atomicAdd(&ws[6], 0.f), s7 = atomicAdd(&ws[7], 0.f);
            float s8 = atomicAdd(&ws[8], 0.f), s9 = atomicAdd(&ws[9], 0.f);
            double vT    = s9;
            double valid = vT + 1e-6;
            double NOd   = (double)NO;
            // repulsion: sum relu(R-d) = hc-weighted (NO^2*R - S) minus diagonal
            double repw  = vT*NOd*NOd*(double)RADIUS_REP - (double)s4;
            double repx  = repw - vT*NOd*((double)RADIUS_REP - 1e-6);
            double loss_cd_hand = ((double)s0 + (double)s1) / (double)(B*NH);
            double loss_cd_obj  = ((double)s2 + (double)s3) / (NOd * valid);
            double loss_rep     = repx / (NOd * NOd * valid);
            double loss_pen     = (double)s5 / (NOd * valid);
            double loss_pose    = (double)s8 / valid;
            double loss_qpos    = (double)s7 / (double)(B*DQ);
            double loss_contact = (double)s6 / (double)(B*NH);
            double total = 5.0*loss_cd_hand + 5.0*loss_cd_obj + 2.0*loss_pose
                         + 1.0*loss_qpos + 2.0*loss_contact
                         + 0.5*loss_rep + 0.5*loss_pen;
            out[0] = (float)total;
        }
    }
}

extern "C" void kernel_launch(void* const* d_in, const int* in_sizes, int n_in,
                              void* d_out, int out_size, void* d_ws, size_t ws_size,
                              hipStream_t stream) {
    const float* pred_hand   = (const float*)d_in[0];
    const float* pred_obj    = (const float*)d_in[1];
    const float* pred_pose   = (const float*)d_in[2];
    const float* pred_qpos   = (const float*)d_in[3];
    const float* logits      = (const float*)d_in[4];
    const float* gt_hand     = (const float*)d_in[5];
    const float* gt_obj      = (const float*)d_in[6];
    const float* gt_pose     = (const float*)d_in[7];
    const float* gt_qpos     = (const float*)d_in[8];
    const float* gt_contact  = (const float*)d_in[9];
    const float* has_contact = (const float*)d_in[10];

    float* ws = (float*)d_ws;

    // single init: scalars+ticket <- 0, rowmin (complement-coded) <- 0
    hipMemsetAsync(ws, 0, (WS_SCAL + ROWS_TOTAL) * sizeof(float), stream);

    pairwise_kernel<<<2051, 256, 0, stream>>>(pred_hand, pred_obj, gt_hand, gt_obj,
                                              has_contact, logits, gt_contact,
                                              pred_qpos, gt_qpos, pred_pose, gt_pose, ws);
    combine_kernel<<<80, 256, 0, stream>>>(has_contact, ws, (float*)d_out);
}